// Round 9
// baseline (2948.368 us; speedup 1.0000x reference)
//
#include <hip/hip_runtime.h>
#include <math.h>

// B=256, T=2048, H=150. Sequential GRU, relu'd hidden, scalar linear head.
// R21 = R20 (verified 1787us) restructured to TWO BATCH ELEMENTS PER BLOCK:
// 128 blocks x 512 threads; block n handles batches 2n, 2n+1.
//   Rationale (counters): wall is dominated by per-iteration FIXED cost
//   (2 barriers, LDS latencies, P2 on 3 of 8 waves) -- VALUBusy only 48%,
//   conflicts at structural floor, and R12->R15 showed issue-count cuts
//   don't move wall. The weight registers (450x152 in v100..v251) are
//   batch-invariant, so each wave runs P1 TWICE (hq0, hq1) back-to-back;
//   P2(b0) on waves 0-2 (tid<150), P2(b1) on waves 3-5 (tid 192..341) --
//   disjoint, concurrent. Fixed cost amortized over 2 recurrences.
//   128 CUs idle by design: latency-bound, not throughput-bound.
// Per-batch arithmetic byte-identical to R20 -> absmax 0.0004882812.

#define BB 256
#define TT 2048
#define HH 150
#define H3 450

typedef float fx2 __attribute__((ext_vector_type(2)));

// Clobber list for explicit weight registers v100..v251.
#define WCLOB \
  "v100","v101","v102","v103","v104","v105","v106","v107","v108","v109", \
  "v110","v111","v112","v113","v114","v115","v116","v117","v118","v119", \
  "v120","v121","v122","v123","v124","v125","v126","v127","v128","v129", \
  "v130","v131","v132","v133","v134","v135","v136","v137","v138","v139", \
  "v140","v141","v142","v143","v144","v145","v146","v147","v148","v149", \
  "v150","v151","v152","v153","v154","v155","v156","v157","v158","v159", \
  "v160","v161","v162","v163","v164","v165","v166","v167","v168","v169", \
  "v170","v171","v172","v173","v174","v175","v176","v177","v178","v179", \
  "v180","v181","v182","v183","v184","v185","v186","v187","v188","v189", \
  "v190","v191","v192","v193","v194","v195","v196","v197","v198","v199", \
  "v200","v201","v202","v203","v204","v205","v206","v207","v208","v209", \
  "v210","v211","v212","v213","v214","v215","v216","v217","v218","v219", \
  "v220","v221","v222","v223","v224","v225","v226","v227","v228","v229", \
  "v230","v231","v232","v233","v234","v235","v236","v237","v238","v239", \
  "v240","v241","v242","v243","v244","v245","v246","v247","v248","v249", \
  "v250","v251"

// Load one k-slot (slot m at byte offset 32*m) for all 8 rows.
#define LD8(a0,a1,b0,b1,c0,c1,d0,d1,OFF) \
  "global_load_dword v" #a0 ", %[p0], off offset:" #OFF "\n\t" \
  "global_load_dword v" #a1 ", %[p1], off offset:" #OFF "\n\t" \
  "global_load_dword v" #b0 ", %[p2], off offset:" #OFF "\n\t" \
  "global_load_dword v" #b1 ", %[p3], off offset:" #OFF "\n\t" \
  "global_load_dword v" #c0 ", %[p4], off offset:" #OFF "\n\t" \
  "global_load_dword v" #c1 ", %[p5], off offset:" #OFF "\n\t" \
  "global_load_dword v" #d0 ", %[p6], off offset:" #OFF "\n\t" \
  "global_load_dword v" #d1 ", %[p7], off offset:" #OFF "\n\t"

// pk_fma with src0-low broadcast to both packed lanes.
#define PKB(sp, vp, acc) \
  "v_pk_fma_f32 " acc ", " sp ", " vp ", " acc " op_sel:[0,0,0] op_sel_hi:[0,1,1]\n\t"
// pk_mul first-touch (no accumulator read): s*A == 0 + s*A bit-exactly.
#define PKM(sp, vp, acc) \
  "v_pk_mul_f32 " acc ", " sp ", " vp " op_sel:[0,0] op_sel_hi:[0,1]\n\t"

#define G4(m0,m1,m2,m3, A0,B0,C0,D0, A1,B1,C1,D1, A2,B2,C2,D2, A3,B3,C3,D3) \
  "v_readlane_b32 s20, %[hq], " #m0 "\n\t" \
  "v_readlane_b32 s22, %[hq], " #m1 "\n\t" \
  "v_readlane_b32 s24, %[hq], " #m2 "\n\t" \
  "v_readlane_b32 s26, %[hq], " #m3 "\n\t" \
  PKB("s[20:21]", A0, "%[a01]") PKB("s[20:21]", B0, "%[a23]") \
  PKB("s[20:21]", C0, "%[a45]") PKB("s[20:21]", D0, "%[a67]") \
  PKB("s[22:23]", A1, "%[a01]") PKB("s[22:23]", B1, "%[a23]") \
  PKB("s[22:23]", C1, "%[a45]") PKB("s[22:23]", D1, "%[a67]") \
  PKB("s[24:25]", A2, "%[a01]") PKB("s[24:25]", B2, "%[a23]") \
  PKB("s[24:25]", C2, "%[a45]") PKB("s[24:25]", D2, "%[a67]") \
  PKB("s[26:27]", A3, "%[a01]") PKB("s[26:27]", B3, "%[a23]") \
  PKB("s[26:27]", C3, "%[a45]") PKB("s[26:27]", D3, "%[a67]")

// First group: slot m0's four ops are pk_mul (chain first touch).
#define G4F(m0,m1,m2,m3, A0,B0,C0,D0, A1,B1,C1,D1, A2,B2,C2,D2, A3,B3,C3,D3) \
  "v_readlane_b32 s20, %[hq], " #m0 "\n\t" \
  "v_readlane_b32 s22, %[hq], " #m1 "\n\t" \
  "v_readlane_b32 s24, %[hq], " #m2 "\n\t" \
  "v_readlane_b32 s26, %[hq], " #m3 "\n\t" \
  PKM("s[20:21]", A0, "%[a01]") PKM("s[20:21]", B0, "%[a23]") \
  PKM("s[20:21]", C0, "%[a45]") PKM("s[20:21]", D0, "%[a67]") \
  PKB("s[22:23]", A1, "%[a01]") PKB("s[22:23]", B1, "%[a23]") \
  PKB("s[22:23]", C1, "%[a45]") PKB("s[22:23]", D1, "%[a67]") \
  PKB("s[24:25]", A2, "%[a01]") PKB("s[24:25]", B2, "%[a23]") \
  PKB("s[24:25]", C2, "%[a45]") PKB("s[24:25]", D2, "%[a67]") \
  PKB("s[26:27]", A3, "%[a01]") PKB("s[26:27]", B3, "%[a23]") \
  PKB("s[26:27]", C3, "%[a45]") PKB("s[26:27]", D3, "%[a67]")

// Full P1 body: 16 k-slots via G4F/G4 + 3-slot tail (19 RL, 76 pk ops).
#define P1ASM(a01v, a23v, a45v, a67v, hqv) \
    asm volatile( \
        G4F( 0, 1, 2, 3, \
            "v[100:101]","v[138:139]","v[176:177]","v[214:215]", \
            "v[102:103]","v[140:141]","v[178:179]","v[216:217]", \
            "v[104:105]","v[142:143]","v[180:181]","v[218:219]", \
            "v[106:107]","v[144:145]","v[182:183]","v[220:221]") \
        G4( 4, 5, 6, 7, \
            "v[108:109]","v[146:147]","v[184:185]","v[222:223]", \
            "v[110:111]","v[148:149]","v[186:187]","v[224:225]", \
            "v[112:113]","v[150:151]","v[188:189]","v[226:227]", \
            "v[114:115]","v[152:153]","v[190:191]","v[228:229]") \
        G4( 8, 9,10,11, \
            "v[116:117]","v[154:155]","v[192:193]","v[230:231]", \
            "v[118:119]","v[156:157]","v[194:195]","v[232:233]", \
            "v[120:121]","v[158:159]","v[196:197]","v[234:235]", \
            "v[122:123]","v[160:161]","v[198:199]","v[236:237]") \
        G4(12,13,14,15, \
            "v[124:125]","v[162:163]","v[200:201]","v[238:239]", \
            "v[126:127]","v[164:165]","v[202:203]","v[240:241]", \
            "v[128:129]","v[166:167]","v[204:205]","v[242:243]", \
            "v[130:131]","v[168:169]","v[206:207]","v[244:245]") \
        "v_readlane_b32 s28, %[hq], 16\n\t" \
        "v_readlane_b32 s30, %[hq], 17\n\t" \
        "v_readlane_b32 s20, %[hq], 18\n\t" \
        PKB("s[28:29]", "v[132:133]", "%[a01]") \
        PKB("s[28:29]", "v[170:171]", "%[a23]") \
        PKB("s[28:29]", "v[208:209]", "%[a45]") \
        PKB("s[28:29]", "v[246:247]", "%[a67]") \
        PKB("s[30:31]", "v[134:135]", "%[a01]") \
        PKB("s[30:31]", "v[172:173]", "%[a23]") \
        PKB("s[30:31]", "v[210:211]", "%[a45]") \
        PKB("s[30:31]", "v[248:249]", "%[a67]") \
        PKB("s[20:21]", "v[136:137]", "%[a01]") \
        PKB("s[20:21]", "v[174:175]", "%[a23]") \
        PKB("s[20:21]", "v[212:213]", "%[a45]") \
        PKB("s[20:21]", "v[250:251]", "%[a67]") \
        : [a01] "=&v"(a01v), [a23] "=&v"(a23v), \
          [a45] "=&v"(a45v), [a67] "=&v"(a67v) \
        : [hq] "v"(hqv) \
        : "s20","s22","s24","s26","s28","s30", WCLOB)

__global__ __launch_bounds__(512, 2) void gru_seq_kernel(
    const float* __restrict__ input,   // [B,T]
    const float* __restrict__ W_ih,    // [450,1]
    const float* __restrict__ W_hh,    // [450,150]
    const float* __restrict__ b_ih,    // [450]
    const float* __restrict__ b_hh,    // [450]
    const float* __restrict__ W_lin,   // [1,150]
    const float* __restrict__ b_lin,   // [1]
    float* __restrict__ out)           // [B,T]
{
    const int b0   = 2 * blockIdx.x;         // batches b0, b0+1
    const int tid  = threadIdx.x;
    const int lane = tid & 63;
    const int wid  = tid >> 6;               // 0..7 = chain (k mod 8)

    __shared__ float xrow[2 * TT];     // 16 KB: two input rows
    __shared__ float PPf[8704];        // 34.8 KB: two partial buffers,
                                       // float2-idx = w*272 + p*68 + lane
                                       // (+2176 float2 for batch 1)
    __shared__ float hb[1280];         // two h buffers: (u&7)*72 + (u>>3)
                                       // (+640 for batch 1)
    __shared__ float yout[2 * TT];     // 16 KB: two y rows

    // ---- prologue -------------------------------------------------------
    ((float4*)xrow)[tid]       = ((const float4*)(input + (size_t)b0 * TT))[tid];
    ((float4*)xrow)[512 + tid] = ((const float4*)(input + (size_t)(b0 + 1) * TT))[tid];
    hb[tid] = 0.f;
    hb[512 + tid] = 0.f;
    if (tid < 256) hb[1024 + tid] = 0.f;

    // Rows 8*lane..8*lane+7. Row 450 = W_lin (y-row). Row >=451: clamp to
    // 449 (junk partials stored but never read).
    const int r0 = 8 * lane;
#define ROWP(r) ((r) == H3 ? W_lin : W_hh + ((r) < H3 ? (r) : (H3 - 1)) * HH)
    const float* p0 = ROWP(r0)     + wid;   // chain w: element k = 8m+w
    const float* p1 = ROWP(r0 + 1) + wid;
    const float* p2 = ROWP(r0 + 2) + wid;
    const float* p3 = ROWP(r0 + 3) + wid;
    const float* p4 = ROWP(r0 + 4) + wid;
    const float* p5 = ROWP(r0 + 5) + wid;
    const float* p6 = ROWP(r0 + 6) + wid;
    const float* p7 = ROWP(r0 + 7) + wid;

    // m = 0..17 into explicit regs, slot m at byte offset 32*m.
    asm volatile(
        LD8(100,101,138,139,176,177,214,215, 0)
        LD8(102,103,140,141,178,179,216,217, 32)
        LD8(104,105,142,143,180,181,218,219, 64)
        LD8(106,107,144,145,182,183,220,221, 96)
        LD8(108,109,146,147,184,185,222,223, 128)
        LD8(110,111,148,149,186,187,224,225, 160)
        LD8(112,113,150,151,188,189,226,227, 192)
        LD8(114,115,152,153,190,191,228,229, 224)
        LD8(116,117,154,155,192,193,230,231, 256)
        LD8(118,119,156,157,194,195,232,233, 288)
        LD8(120,121,158,159,196,197,234,235, 320)
        LD8(122,123,160,161,198,199,236,237, 352)
        LD8(124,125,162,163,200,201,238,239, 384)
        LD8(126,127,164,165,202,203,240,241, 416)
        LD8(128,129,166,167,204,205,242,243, 448)
        LD8(130,131,168,169,206,207,244,245, 480)
        LD8(132,133,170,171,208,209,246,247, 512)
        LD8(134,135,172,173,210,211,248,249, 544)
        "s_waitcnt vmcnt(0)\n\t"
        :
        : [p0] "v"(p0), [p1] "v"(p1), [p2] "v"(p2), [p3] "v"(p3),
          [p4] "v"(p4), [p5] "v"(p5), [p6] "v"(p6), [p7] "v"(p7)
        : WCLOB, "memory");
    // m = 18: k = 144+wid. Real for wid<6; for wid>=6 h[150..151]=0 forever
    // (hb slots never written in either buffer), so load in-bounds junk.
    {
        const int t18 = (wid < 6) ? 144 : 136;
        float w0 = p0[t18], w1 = p1[t18], w2 = p2[t18], w3 = p3[t18];
        float w4 = p4[t18], w5 = p5[t18], w6 = p6[t18], w7 = p7[t18];
        asm volatile(
            "v_mov_b32 v136, %0\n\tv_mov_b32 v137, %1\n\t"
            "v_mov_b32 v174, %2\n\tv_mov_b32 v175, %3\n\t"
            "v_mov_b32 v212, %4\n\tv_mov_b32 v213, %5\n\t"
            "v_mov_b32 v250, %6\n\tv_mov_b32 v251, %7\n\t"
            :: "v"(w0), "v"(w1), "v"(w2), "v"(w3),
               "v"(w4), "v"(w5), "v"(w6), "v"(w7)
            : "v136","v137","v174","v175","v212","v213","v250","v251");
    }

    // P2 roles: batch0 gates on tid<150 (waves 0-2); batch1 gates on
    // tid in [192, 342) (waves 3-5). Same variables, role-selected values.
    const bool p2a = (tid < HH);
    const bool p2b = (tid >= 192) && (tid < 192 + HH);
    const int  u   = p2b ? (tid - 192) : tid;   // unit id (valid if p2a|p2b)
    float wih_r = 0.f, wih_z = 0.f, wih_n = 0.f;
    float bih_r = 0.f, bih_z = 0.f, bih_n = 0.f;
    float bhh_r = 0.f, bhh_z = 0.f, bhh_n = 0.f;
    if (p2a || p2b) {
        wih_r = W_ih[u];          bih_r = b_ih[u];          bhh_r = b_hh[u];
        wih_z = W_ih[HH + u];     bih_z = b_ih[HH + u];     bhh_z = b_hh[HH + u];
        wih_n = W_ih[2 * HH + u]; bih_n = b_ih[2 * HH + u]; bhh_n = b_hh[2 * HH + u];
    }
    const float blin = b_lin[0];
    float hreg = 0.f;
    // Store pointer: 4 float2 (8B lane stride = 2-way alias = free);
    // batch-1 stores at +2176 float2 (compile-time immediates).
    float2* st = (float2*)PPf + wid * 272 + lane;
    // P2 read indices (stride-68 geometry, 2-way everywhere); +4352 floats
    // for batch-1 readers.
    int ir = 0, iz = 0, in_ = 0;
    if (p2a || p2b) {
        int r;
        r = u;          ir  = (((r & 7) >> 1) * 68 + (r >> 3)) * 2 + (r & 1);
        r = HH + u;     iz  = (((r & 7) >> 1) * 68 + (r >> 3)) * 2 + (r & 1);
        r = 2*HH + u;   in_ = (((r & 7) >> 1) * 68 + (r >> 3)) * 2 + (r & 1);
        if (p2b) { ir += 4352; iz += 4352; in_ += 4352; }
    }
    const int xoff = p2b ? TT : 0;               // x source row
    const int hbw  = (p2b ? 640 : 0) + (u & 7) * 72 + (u >> 3);
    // y writers: tid 450 -> batch0 (buffer 0), tid 451 -> batch1 (buffer 1).
    const bool yw   = (tid == H3) || (tid == H3 + 1);
    const int  iy   = (1 * 68 + 56) * 2 + ((tid == H3 + 1) ? 4352 : 0);
    const int  yoff = (tid == H3 + 1) ? TT : 0;

    __syncthreads();

    // ---- recurrence -----------------------------------------------------
    // Iteration t: P1(b0)+P1(b1) per wave (shared weight regs), barrier,
    // P2(b0)||P2(b1) on disjoint waves, barrier. Extra iter t==TT for y.
    for (int t = 0; t <= TT; ++t) {
        float hq0 = hb[wid * 72 + lane];
        float hq1 = hb[640 + wid * 72 + lane];
        {
            fx2 a01, a23, a45, a67;
            P1ASM(a01, a23, a45, a67, hq0);
            float2 s01; s01.x = a01.x; s01.y = a01.y;
            float2 s23; s23.x = a23.x; s23.y = a23.y;
            float2 s45; s45.x = a45.x; s45.y = a45.y;
            float2 s67; s67.x = a67.x; s67.y = a67.y;
            st[0]   = s01;
            st[68]  = s23;
            st[136] = s45;
            st[204] = s67;
        }
        {
            fx2 a01, a23, a45, a67;
            P1ASM(a01, a23, a45, a67, hq1);
            float2 s01; s01.x = a01.x; s01.y = a01.y;
            float2 s23; s23.x = a23.x; s23.y = a23.y;
            float2 s45; s45.x = a45.x; s45.y = a45.y;
            float2 s67; s67.x = a67.x; s67.y = a67.y;
            st[2176]       = s01;
            st[2176 + 68]  = s23;
            st[2176 + 136] = s45;
            st[2176 + 204] = s67;
        }
        __syncthreads();

        // phase 2: gates + hidden update, both batches on disjoint waves.
        if (t < TT && (p2a || p2b)) {
            float x  = xrow[xoff + t];
            float pr = (((PPf[ir]         + PPf[ir + 544])
                       + (PPf[ir + 1088]  + PPf[ir + 1632]))
                      + ((PPf[ir + 2176]  + PPf[ir + 2720])
                       + (PPf[ir + 3264]  + PPf[ir + 3808]))) + bhh_r;
            float pz = (((PPf[iz]         + PPf[iz + 544])
                       + (PPf[iz + 1088]  + PPf[iz + 1632]))
                      + ((PPf[iz + 2176]  + PPf[iz + 2720])
                       + (PPf[iz + 3264]  + PPf[iz + 3808]))) + bhh_z;
            float pn = (((PPf[in_]        + PPf[in_ + 544])
                       + (PPf[in_ + 1088] + PPf[in_ + 1632]))
                      + ((PPf[in_ + 2176] + PPf[in_ + 2720])
                       + (PPf[in_ + 3264] + PPf[in_ + 3808]))) + bhh_n;
            float gr = fmaf(x, wih_r, bih_r) + pr;
            float gz = fmaf(x, wih_z, bih_z) + pz;
            float r  = 1.f / (1.f + __expf(-gr));
            float z  = 1.f / (1.f + __expf(-gz));
            float ta = fmaf(x, wih_n, bih_n) + r * pn;
            ta = fminf(fmaxf(ta, -15.f), 15.f);
            float e  = __expf(2.f * ta);
            float n  = (e - 1.f) / (e + 1.f);        // tanh
            float hnew = fmaf(z, hreg - n, n);       // (1-z)*n + z*h
            hnew = fmaxf(hnew, 0.f);                 // relu
            hreg = hnew;
            hb[hbw] = hnew;                          // 2-way write alias
        }
        // y_{t-1} from row 450 (same 8-term tree): tid 450 = b0, 451 = b1.
        if (t > 0 && yw) {
            yout[yoff + t - 1] = (((PPf[iy]        + PPf[iy + 544])
                                 + (PPf[iy + 1088] + PPf[iy + 1632]))
                                + ((PPf[iy + 2176] + PPf[iy + 2720])
                                 + (PPf[iy + 3264] + PPf[iy + 3808]))) + blin;
        }
        __syncthreads();
    }

    // ---- epilogue: coalesced y dump for both rows ------------------------
    ((float4*)(out + (size_t)b0 * TT))[tid]       = ((const float4*)yout)[tid];
    ((float4*)(out + (size_t)(b0 + 1) * TT))[tid] = ((const float4*)(yout + TT))[tid];
}

extern "C" void kernel_launch(void* const* d_in, const int* in_sizes, int n_in,
                              void* d_out, int out_size, void* d_ws, size_t ws_size,
                              hipStream_t stream) {
    const float* input = (const float*)d_in[0];
    const float* W_ih  = (const float*)d_in[1];
    const float* W_hh  = (const float*)d_in[2];
    const float* b_ih  = (const float*)d_in[3];
    const float* b_hh  = (const float*)d_in[4];
    const float* W_lin = (const float*)d_in[5];
    const float* b_lin = (const float*)d_in[6];
    float* out = (float*)d_out;

    gru_seq_kernel<<<dim3(BB / 2), dim3(512), 0, stream>>>(
        input, W_ih, W_hh, b_ih, b_hh, W_lin, b_lin, out);
}

// Round 10
// 1787.584 us; speedup vs baseline: 1.6494x; 1.6494x over previous
//
#include <hip/hip_runtime.h>
#include <math.h>

// B=256, T=2048, H=150. Sequential GRU, relu'd hidden, scalar linear head.
// 1 block / batch element (256 blocks = 256 CUs), 512 threads.
//
// R22 = R20 = R18 verbatim (verified best: 1787/1788us, absmax 4.88e-4).
// R21 (2 batches/block, shared weight regs) regressed 1.65x: v_pk_fma_f32
// is ~4cyc/wave64 (packed = 2 ops), so P1 is ~600cyc/SIMD of the ~2100cyc
// iteration -- doubling it lands straight on the critical path. Reverted.
//
// Structure: 8-chain P1 (wave w = chain k%8, lane l = rows 8l..8l+7,
// 19 readlanes + 76 broadcast-pk_fmas per wave, PKM first-touch),
// stride-68/72 bank-free LDS geometry (2-way = structural wave64
// minimum), two barriers, P2 concentrated on tid<150.
// Ledger (all measured): P1 batching +65% (R21); P2 spread +9/+15%
// (R13/R16); LDS atomics 6.6x (R19); issue micros neutral (R15/R18);
// bank geometry solved (R17). This is the latency-structure floor of
// the fp32 decomposition.

#define BB 256
#define TT 2048
#define HH 150
#define H3 450

typedef float fx2 __attribute__((ext_vector_type(2)));

// Clobber list for explicit weight registers v100..v251.
#define WCLOB \
  "v100","v101","v102","v103","v104","v105","v106","v107","v108","v109", \
  "v110","v111","v112","v113","v114","v115","v116","v117","v118","v119", \
  "v120","v121","v122","v123","v124","v125","v126","v127","v128","v129", \
  "v130","v131","v132","v133","v134","v135","v136","v137","v138","v139", \
  "v140","v141","v142","v143","v144","v145","v146","v147","v148","v149", \
  "v150","v151","v152","v153","v154","v155","v156","v157","v158","v159", \
  "v160","v161","v162","v163","v164","v165","v166","v167","v168","v169", \
  "v170","v171","v172","v173","v174","v175","v176","v177","v178","v179", \
  "v180","v181","v182","v183","v184","v185","v186","v187","v188","v189", \
  "v190","v191","v192","v193","v194","v195","v196","v197","v198","v199", \
  "v200","v201","v202","v203","v204","v205","v206","v207","v208","v209", \
  "v210","v211","v212","v213","v214","v215","v216","v217","v218","v219", \
  "v220","v221","v222","v223","v224","v225","v226","v227","v228","v229", \
  "v230","v231","v232","v233","v234","v235","v236","v237","v238","v239", \
  "v240","v241","v242","v243","v244","v245","v246","v247","v248","v249", \
  "v250","v251"

// Load one k-slot (slot m at byte offset 32*m) for all 8 rows.
#define LD8(a0,a1,b0,b1,c0,c1,d0,d1,OFF) \
  "global_load_dword v" #a0 ", %[p0], off offset:" #OFF "\n\t" \
  "global_load_dword v" #a1 ", %[p1], off offset:" #OFF "\n\t" \
  "global_load_dword v" #b0 ", %[p2], off offset:" #OFF "\n\t" \
  "global_load_dword v" #b1 ", %[p3], off offset:" #OFF "\n\t" \
  "global_load_dword v" #c0 ", %[p4], off offset:" #OFF "\n\t" \
  "global_load_dword v" #c1 ", %[p5], off offset:" #OFF "\n\t" \
  "global_load_dword v" #d0 ", %[p6], off offset:" #OFF "\n\t" \
  "global_load_dword v" #d1 ", %[p7], off offset:" #OFF "\n\t"

// pk_fma with src0-low broadcast to both packed lanes.
#define PKB(sp, vp, acc) \
  "v_pk_fma_f32 " acc ", " sp ", " vp ", " acc " op_sel:[0,0,0] op_sel_hi:[0,1,1]\n\t"
// pk_mul first-touch (no accumulator read): s*A == 0 + s*A bit-exactly.
#define PKM(sp, vp, acc) \
  "v_pk_mul_f32 " acc ", " sp ", " vp " op_sel:[0,0] op_sel_hi:[0,1]\n\t"

// 4 k-slots: 4 readlanes (even SGPRs) then 16 broadcast-pk_fmas (4 accum
// chains). First consumer of s20 is 4 insts after its write.
#define G4(m0,m1,m2,m3, A0,B0,C0,D0, A1,B1,C1,D1, A2,B2,C2,D2, A3,B3,C3,D3) \
  "v_readlane_b32 s20, %[hq], " #m0 "\n\t" \
  "v_readlane_b32 s22, %[hq], " #m1 "\n\t" \
  "v_readlane_b32 s24, %[hq], " #m2 "\n\t" \
  "v_readlane_b32 s26, %[hq], " #m3 "\n\t" \
  PKB("s[20:21]", A0, "%[a01]") PKB("s[20:21]", B0, "%[a23]") \
  PKB("s[20:21]", C0, "%[a45]") PKB("s[20:21]", D0, "%[a67]") \
  PKB("s[22:23]", A1, "%[a01]") PKB("s[22:23]", B1, "%[a23]") \
  PKB("s[22:23]", C1, "%[a45]") PKB("s[22:23]", D1, "%[a67]") \
  PKB("s[24:25]", A2, "%[a01]") PKB("s[24:25]", B2, "%[a23]") \
  PKB("s[24:25]", C2, "%[a45]") PKB("s[24:25]", D2, "%[a67]") \
  PKB("s[26:27]", A3, "%[a01]") PKB("s[26:27]", B3, "%[a23]") \
  PKB("s[26:27]", C3, "%[a45]") PKB("s[26:27]", D3, "%[a67]")

// First group: slot m0's four ops are pk_mul (chain first touch).
#define G4F(m0,m1,m2,m3, A0,B0,C0,D0, A1,B1,C1,D1, A2,B2,C2,D2, A3,B3,C3,D3) \
  "v_readlane_b32 s20, %[hq], " #m0 "\n\t" \
  "v_readlane_b32 s22, %[hq], " #m1 "\n\t" \
  "v_readlane_b32 s24, %[hq], " #m2 "\n\t" \
  "v_readlane_b32 s26, %[hq], " #m3 "\n\t" \
  PKM("s[20:21]", A0, "%[a01]") PKM("s[20:21]", B0, "%[a23]") \
  PKM("s[20:21]", C0, "%[a45]") PKM("s[20:21]", D0, "%[a67]") \
  PKB("s[22:23]", A1, "%[a01]") PKB("s[22:23]", B1, "%[a23]") \
  PKB("s[22:23]", C1, "%[a45]") PKB("s[22:23]", D1, "%[a67]") \
  PKB("s[24:25]", A2, "%[a01]") PKB("s[24:25]", B2, "%[a23]") \
  PKB("s[24:25]", C2, "%[a45]") PKB("s[24:25]", D2, "%[a67]") \
  PKB("s[26:27]", A3, "%[a01]") PKB("s[26:27]", B3, "%[a23]") \
  PKB("s[26:27]", C3, "%[a45]") PKB("s[26:27]", D3, "%[a67]")

__global__ __launch_bounds__(512, 2) void gru_seq_kernel(
    const float* __restrict__ input,   // [B,T]
    const float* __restrict__ W_ih,    // [450,1]
    const float* __restrict__ W_hh,    // [450,150]
    const float* __restrict__ b_ih,    // [450]
    const float* __restrict__ b_hh,    // [450]
    const float* __restrict__ W_lin,   // [1,150]
    const float* __restrict__ b_lin,   // [1]
    float* __restrict__ out)           // [B,T]
{
    const int b    = blockIdx.x;
    const int tid  = threadIdx.x;
    const int lane = tid & 63;
    const int wid  = tid >> 6;               // 0..7 = chain (k mod 8)

    __shared__ float xrow[TT];         // 8 KB input row
    __shared__ float PPf[4352];        // 17.4 KB partials:
                                       // float2-idx = w*272 + p*68 + lane,
                                       // p = pair (rows 8l+2p, 8l+2p+1)
    __shared__ float hb[640];          // h swizzled: hb[(u&7)*72 + (u>>3)]
    __shared__ float yout[TT];         // 8 KB y buffer

    // ---- prologue -------------------------------------------------------
    ((float4*)xrow)[tid] = ((const float4*)(input + (size_t)b * TT))[tid];
    hb[tid] = 0.f;                     // 0..511
    if (tid < 128) hb[512 + tid] = 0.f;

    // Rows 8*lane..8*lane+7. Row 450 = W_lin (y-row). Row >=451: clamp to
    // 449 (junk partials stored but never read).
    const int r0 = 8 * lane;
#define ROWP(r) ((r) == H3 ? W_lin : W_hh + ((r) < H3 ? (r) : (H3 - 1)) * HH)
    const float* p0 = ROWP(r0)     + wid;   // chain w: element k = 8m+w
    const float* p1 = ROWP(r0 + 1) + wid;
    const float* p2 = ROWP(r0 + 2) + wid;
    const float* p3 = ROWP(r0 + 3) + wid;
    const float* p4 = ROWP(r0 + 4) + wid;
    const float* p5 = ROWP(r0 + 5) + wid;
    const float* p6 = ROWP(r0 + 6) + wid;
    const float* p7 = ROWP(r0 + 7) + wid;

    // m = 0..17 into explicit regs, slot m at byte offset 32*m. Pair-sets
    // (even-aligned): A rows (j0,j1) = v[100+2m], B (j2,j3) = v[138+2m],
    // C (j4,j5) = v[176+2m], D (j6,j7) = v[214+2m].
    asm volatile(
        LD8(100,101,138,139,176,177,214,215, 0)
        LD8(102,103,140,141,178,179,216,217, 32)
        LD8(104,105,142,143,180,181,218,219, 64)
        LD8(106,107,144,145,182,183,220,221, 96)
        LD8(108,109,146,147,184,185,222,223, 128)
        LD8(110,111,148,149,186,187,224,225, 160)
        LD8(112,113,150,151,188,189,226,227, 192)
        LD8(114,115,152,153,190,191,228,229, 224)
        LD8(116,117,154,155,192,193,230,231, 256)
        LD8(118,119,156,157,194,195,232,233, 288)
        LD8(120,121,158,159,196,197,234,235, 320)
        LD8(122,123,160,161,198,199,236,237, 352)
        LD8(124,125,162,163,200,201,238,239, 384)
        LD8(126,127,164,165,202,203,240,241, 416)
        LD8(128,129,166,167,204,205,242,243, 448)
        LD8(130,131,168,169,206,207,244,245, 480)
        LD8(132,133,170,171,208,209,246,247, 512)
        LD8(134,135,172,173,210,211,248,249, 544)
        "s_waitcnt vmcnt(0)\n\t"
        :
        : [p0] "v"(p0), [p1] "v"(p1), [p2] "v"(p2), [p3] "v"(p3),
          [p4] "v"(p4), [p5] "v"(p5), [p6] "v"(p6), [p7] "v"(p7)
        : WCLOB, "memory");
    // m = 18: k = 144+wid. Real for wid<6; for wid>=6 h[150..151]=0 forever
    // (hb slots never written), so load in-bounds junk (k=136+wid).
    {
        const int t18 = (wid < 6) ? 144 : 136;
        float w0 = p0[t18], w1 = p1[t18], w2 = p2[t18], w3 = p3[t18];
        float w4 = p4[t18], w5 = p5[t18], w6 = p6[t18], w7 = p7[t18];
        asm volatile(
            "v_mov_b32 v136, %0\n\tv_mov_b32 v137, %1\n\t"
            "v_mov_b32 v174, %2\n\tv_mov_b32 v175, %3\n\t"
            "v_mov_b32 v212, %4\n\tv_mov_b32 v213, %5\n\t"
            "v_mov_b32 v250, %6\n\tv_mov_b32 v251, %7\n\t"
            :: "v"(w0), "v"(w1), "v"(w2), "v"(w3),
               "v"(w4), "v"(w5), "v"(w6), "v"(w7)
            : "v136","v137","v174","v175","v212","v213","v250","v251");
    }

    // Phase-2 constants (threads 0..149) -- gate math verbatim from R12.
    float wih_r = 0.f, wih_z = 0.f, wih_n = 0.f;
    float bih_r = 0.f, bih_z = 0.f, bih_n = 0.f;
    float bhh_r = 0.f, bhh_z = 0.f, bhh_n = 0.f;
    if (tid < HH) {
        wih_r = W_ih[tid];          bih_r = b_ih[tid];          bhh_r = b_hh[tid];
        wih_z = W_ih[HH + tid];     bih_z = b_ih[HH + tid];     bhh_z = b_hh[HH + tid];
        wih_n = W_ih[2 * HH + tid]; bih_n = b_ih[2 * HH + tid]; bhh_n = b_hh[2 * HH + tid];
    }
    const float blin = b_lin[0];
    float hreg = 0.f;
    float* outb = out + (size_t)b * TT;
    // Store pointer: 4 float2 (8B lane stride = 2-way alias = free).
    float2* st = (float2*)PPf + wid * 272 + lane;
    // Phase-2 read indices: row r -> float idx (((r&7)>>1)*68 + (r>>3))*2
    // + (r&1); chain offset +544 floats each. bank = (8p+2d+c) mod 32 over
    // a wave's (p,d,c) space = exactly 2-way (free).
    int ir = 0, iz = 0, in_ = 0;
    if (tid < HH) {
        int r;
        r = tid;        ir  = (((r & 7) >> 1) * 68 + (r >> 3)) * 2 + (r & 1);
        r = HH + tid;   iz  = (((r & 7) >> 1) * 68 + (r >> 3)) * 2 + (r & 1);
        r = 2*HH + tid; in_ = (((r & 7) >> 1) * 68 + (r >> 3)) * 2 + (r & 1);
    }
    const int iy = (1 * 68 + 56) * 2;   // row 450: p=1, g=56, c=0 -> 248

    __syncthreads();

    // ---- recurrence -----------------------------------------------------
    // Iteration t dots h_{t-1}; row 450 gives y_{t-1}. Extra iteration
    // t==TT supplies y_{TT-1}; its h-update is guarded off.
    for (int t = 0; t <= TT; ++t) {
        // phase 1: chain w of rows 8l..8l+7. hq = hb[w][lane] = h[8*lane+w],
        // conflict-free stride-1-bank b32 read.
        float hq = hb[wid * 72 + lane];
        fx2 a01, a23, a45, a67;        // first-touched by PKM in slot 0
        asm volatile(
            G4F( 0, 1, 2, 3,
                "v[100:101]","v[138:139]","v[176:177]","v[214:215]",
                "v[102:103]","v[140:141]","v[178:179]","v[216:217]",
                "v[104:105]","v[142:143]","v[180:181]","v[218:219]",
                "v[106:107]","v[144:145]","v[182:183]","v[220:221]")
            G4( 4, 5, 6, 7,
                "v[108:109]","v[146:147]","v[184:185]","v[222:223]",
                "v[110:111]","v[148:149]","v[186:187]","v[224:225]",
                "v[112:113]","v[150:151]","v[188:189]","v[226:227]",
                "v[114:115]","v[152:153]","v[190:191]","v[228:229]")
            G4( 8, 9,10,11,
                "v[116:117]","v[154:155]","v[192:193]","v[230:231]",
                "v[118:119]","v[156:157]","v[194:195]","v[232:233]",
                "v[120:121]","v[158:159]","v[196:197]","v[234:235]",
                "v[122:123]","v[160:161]","v[198:199]","v[236:237]")
            G4(12,13,14,15,
                "v[124:125]","v[162:163]","v[200:201]","v[238:239]",
                "v[126:127]","v[164:165]","v[202:203]","v[240:241]",
                "v[128:129]","v[166:167]","v[204:205]","v[242:243]",
                "v[130:131]","v[168:169]","v[206:207]","v[244:245]")
            // tail: slots 16,17,18 -- 3 readlanes then 12 pk_fmas.
            "v_readlane_b32 s28, %[hq], 16\n\t"
            "v_readlane_b32 s30, %[hq], 17\n\t"
            "v_readlane_b32 s20, %[hq], 18\n\t"
            PKB("s[28:29]", "v[132:133]", "%[a01]")
            PKB("s[28:29]", "v[170:171]", "%[a23]")
            PKB("s[28:29]", "v[208:209]", "%[a45]")
            PKB("s[28:29]", "v[246:247]", "%[a67]")
            PKB("s[30:31]", "v[134:135]", "%[a01]")
            PKB("s[30:31]", "v[172:173]", "%[a23]")
            PKB("s[30:31]", "v[210:211]", "%[a45]")
            PKB("s[30:31]", "v[248:249]", "%[a67]")
            PKB("s[20:21]", "v[136:137]", "%[a01]")
            PKB("s[20:21]", "v[174:175]", "%[a23]")
            PKB("s[20:21]", "v[212:213]", "%[a45]")
            PKB("s[20:21]", "v[250:251]", "%[a67]")
            : [a01] "=&v"(a01), [a23] "=&v"(a23),
              [a45] "=&v"(a45), [a67] "=&v"(a67)
            : [hq] "v"(hq)
            : "s20","s22","s24","s26","s28","s30", WCLOB);
        // Four conflict-free b64 stores (8B lane stride).
        float2 s01; s01.x = a01.x; s01.y = a01.y;
        float2 s23; s23.x = a23.x; s23.y = a23.y;
        float2 s45; s45.x = a45.x; s45.y = a45.y;
        float2 s67; s67.x = a67.x; s67.y = a67.y;
        st[0]   = s01;
        st[68]  = s23;
        st[136] = s45;
        st[204] = s67;
        __syncthreads();

        // phase 2: gates + hidden update (threads 0..149), skipped at t==TT.
        // pre_row = (((c0+c1)+(c2+c3)) + ((c4+c5)+(c6+c7))) + bhh.
        if (t < TT && tid < HH) {
            float x  = xrow[t];
            float pr = (((PPf[ir]         + PPf[ir + 544])
                       + (PPf[ir + 1088]  + PPf[ir + 1632]))
                      + ((PPf[ir + 2176]  + PPf[ir + 2720])
                       + (PPf[ir + 3264]  + PPf[ir + 3808]))) + bhh_r;
            float pz = (((PPf[iz]         + PPf[iz + 544])
                       + (PPf[iz + 1088]  + PPf[iz + 1632]))
                      + ((PPf[iz + 2176]  + PPf[iz + 2720])
                       + (PPf[iz + 3264]  + PPf[iz + 3808]))) + bhh_z;
            float pn = (((PPf[in_]        + PPf[in_ + 544])
                       + (PPf[in_ + 1088] + PPf[in_ + 1632]))
                      + ((PPf[in_ + 2176] + PPf[in_ + 2720])
                       + (PPf[in_ + 3264] + PPf[in_ + 3808]))) + bhh_n;
            float gr = fmaf(x, wih_r, bih_r) + pr;
            float gz = fmaf(x, wih_z, bih_z) + pz;
            float r  = 1.f / (1.f + __expf(-gr));
            float z  = 1.f / (1.f + __expf(-gz));
            float ta = fmaf(x, wih_n, bih_n) + r * pn;
            ta = fminf(fmaxf(ta, -15.f), 15.f);
            float e  = __expf(2.f * ta);
            float n  = (e - 1.f) / (e + 1.f);        // tanh
            float hnew = fmaf(z, hreg - n, n);       // (1-z)*n + z*h
            hnew = fmaxf(hnew, 0.f);                 // relu
            hreg = hnew;
            hb[(tid & 7) * 72 + (tid >> 3)] = hnew;  // 2-way write alias
        }
        // y_{t-1} from phase-1 row 450 (same 8-term tree), wave 7.
        if (t > 0 && tid == H3) {
            yout[t - 1] = (((PPf[iy]        + PPf[iy + 544])
                          + (PPf[iy + 1088] + PPf[iy + 1632]))
                         + ((PPf[iy + 2176] + PPf[iy + 2720])
                          + (PPf[iy + 3264] + PPf[iy + 3808]))) + blin;
        }
        __syncthreads();
    }

    // ---- epilogue: coalesced y dump (the loop's only global write) -------
    ((float4*)outb)[tid] = ((const float4*)yout)[tid];
}

extern "C" void kernel_launch(void* const* d_in, const int* in_sizes, int n_in,
                              void* d_out, int out_size, void* d_ws, size_t ws_size,
                              hipStream_t stream) {
    const float* input = (const float*)d_in[0];
    const float* W_ih  = (const float*)d_in[1];
    const float* W_hh  = (const float*)d_in[2];
    const float* b_ih  = (const float*)d_in[3];
    const float* b_hh  = (const float*)d_in[4];
    const float* W_lin = (const float*)d_in[5];
    const float* b_lin = (const float*)d_in[6];
    float* out = (float*)d_out;

    gru_seq_kernel<<<dim3(BB), dim3(512), 0, stream>>>(
        input, W_ih, W_hh, b_ih, b_hh, W_lin, b_lin, out);
}

// Round 11
// 1660.592 us; speedup vs baseline: 1.7755x; 1.0765x over previous
//
#include <hip/hip_runtime.h>
#include <math.h>

// B=256, T=2048, H=150. Sequential GRU, relu'd hidden, scalar linear head.
// 1 block / batch element (256 blocks = 256 CUs), 512 threads.
//
// R23 = R22 (verified 1787us x3) with the h-broadcast transport replaced:
//   OLD: 64-wide ds_read of hq (120cy exposed at P1 head) + 19 v_readlane
//        (38cy issue + VALU->SGPR->VALU hazards) per wave.
//   NEW: 10 ds_read_b64 at a WAVE-UNIFORM address (hb + wid*288, offsets
//        0..72) -- LDS same-address reads broadcast conflict-free. Each
//        even-aligned VGPR pair holds (h[8m+w], h[8m+8+w]); pk_fma op_sel
//        picks low/high word as the broadcast scalar (same mechanism as
//        the old s[20:21] usage, VGPR-sourced). Counted lgkmcnt(8/6/4/2/0)
//        pipelines loads under MACs; counts are tail-robust to any
//        compiler-pre-issued DS loads (ours are last in the in-order
//        queue). No readlanes, no SGPR clobbers, no exposed wide-read.
// Operand values and per-chain accumulation order bit-identical to R22
// -> absmax 0.0004882812.
// Ledger: P1 batching +65% (R21); P2 spread +9/+15% (R13/R16); LDS
// atomics 6.6x (R19); issue micros neutral (R15/R18); bank geometry
// solved (R17, 2-way structural floor).

#define BB 256
#define TT 2048
#define HH 150
#define H3 450

typedef float fx2 __attribute__((ext_vector_type(2)));

// Clobber list for explicit weight registers v100..v251.
#define WCLOB \
  "v100","v101","v102","v103","v104","v105","v106","v107","v108","v109", \
  "v110","v111","v112","v113","v114","v115","v116","v117","v118","v119", \
  "v120","v121","v122","v123","v124","v125","v126","v127","v128","v129", \
  "v130","v131","v132","v133","v134","v135","v136","v137","v138","v139", \
  "v140","v141","v142","v143","v144","v145","v146","v147","v148","v149", \
  "v150","v151","v152","v153","v154","v155","v156","v157","v158","v159", \
  "v160","v161","v162","v163","v164","v165","v166","v167","v168","v169", \
  "v170","v171","v172","v173","v174","v175","v176","v177","v178","v179", \
  "v180","v181","v182","v183","v184","v185","v186","v187","v188","v189", \
  "v190","v191","v192","v193","v194","v195","v196","v197","v198","v199", \
  "v200","v201","v202","v203","v204","v205","v206","v207","v208","v209", \
  "v210","v211","v212","v213","v214","v215","v216","v217","v218","v219", \
  "v220","v221","v222","v223","v224","v225","v226","v227","v228","v229", \
  "v230","v231","v232","v233","v234","v235","v236","v237","v238","v239", \
  "v240","v241","v242","v243","v244","v245","v246","v247","v248","v249", \
  "v250","v251"

// h-broadcast scratch pairs v[80:81]..v[98:99].
#define HCLOB \
  "v80","v81","v82","v83","v84","v85","v86","v87","v88","v89", \
  "v90","v91","v92","v93","v94","v95","v96","v97","v98","v99"

// Load one k-slot (slot m at byte offset 32*m) for all 8 rows.
#define LD8(a0,a1,b0,b1,c0,c1,d0,d1,OFF) \
  "global_load_dword v" #a0 ", %[p0], off offset:" #OFF "\n\t" \
  "global_load_dword v" #a1 ", %[p1], off offset:" #OFF "\n\t" \
  "global_load_dword v" #b0 ", %[p2], off offset:" #OFF "\n\t" \
  "global_load_dword v" #b1 ", %[p3], off offset:" #OFF "\n\t" \
  "global_load_dword v" #c0 ", %[p4], off offset:" #OFF "\n\t" \
  "global_load_dword v" #c1 ", %[p5], off offset:" #OFF "\n\t" \
  "global_load_dword v" #d0 ", %[p6], off offset:" #OFF "\n\t" \
  "global_load_dword v" #d1 ", %[p7], off offset:" #OFF "\n\t"

// pk_fma / pk_mul with broadcast from LOW or HIGH word of VGPR pair hp.
#define PKBL(hp, wp, acc) \
  "v_pk_fma_f32 " acc ", " hp ", " wp ", " acc " op_sel:[0,0,0] op_sel_hi:[0,1,1]\n\t"
#define PKBH(hp, wp, acc) \
  "v_pk_fma_f32 " acc ", " hp ", " wp ", " acc " op_sel:[1,0,0] op_sel_hi:[1,1,1]\n\t"
#define PKML(hp, wp, acc) \
  "v_pk_mul_f32 " acc ", " hp ", " wp " op_sel:[0,0] op_sel_hi:[0,1]\n\t"

// One k-slot = 4 chains. S0 = first touch (pk_mul), SL = low word,
// SH = high word of the h pair.
#define S0(P, A,B,C,D) \
  PKML(P, A, "%[a01]") PKML(P, B, "%[a23]") \
  PKML(P, C, "%[a45]") PKML(P, D, "%[a67]")
#define SL(P, A,B,C,D) \
  PKBL(P, A, "%[a01]") PKBL(P, B, "%[a23]") \
  PKBL(P, C, "%[a45]") PKBL(P, D, "%[a67]")
#define SH(P, A,B,C,D) \
  PKBH(P, A, "%[a01]") PKBH(P, B, "%[a23]") \
  PKBH(P, C, "%[a45]") PKBH(P, D, "%[a67]")

__global__ __launch_bounds__(512, 2) void gru_seq_kernel(
    const float* __restrict__ input,   // [B,T]
    const float* __restrict__ W_ih,    // [450,1]
    const float* __restrict__ W_hh,    // [450,150]
    const float* __restrict__ b_ih,    // [450]
    const float* __restrict__ b_hh,    // [450]
    const float* __restrict__ W_lin,   // [1,150]
    const float* __restrict__ b_lin,   // [1]
    float* __restrict__ out)           // [B,T]
{
    const int b    = blockIdx.x;
    const int tid  = threadIdx.x;
    const int lane = tid & 63;
    const int wid  = tid >> 6;               // 0..7 = chain (k mod 8)

    __shared__ float xrow[TT];         // 8 KB input row
    __shared__ float PPf[4352];        // 17.4 KB partials:
                                       // float2-idx = w*272 + p*68 + lane
    __shared__ __align__(16) float hb[640];  // h: hb[(u&7)*72 + (u>>3)]
    __shared__ float yout[TT];         // 8 KB y buffer

    // ---- prologue -------------------------------------------------------
    ((float4*)xrow)[tid] = ((const float4*)(input + (size_t)b * TT))[tid];
    hb[tid] = 0.f;                     // 0..511
    if (tid < 128) hb[512 + tid] = 0.f;

    // Rows 8*lane..8*lane+7. Row 450 = W_lin (y-row). Row >=451: clamp to
    // 449 (junk partials stored but never read).
    const int r0 = 8 * lane;
#define ROWP(r) ((r) == H3 ? W_lin : W_hh + ((r) < H3 ? (r) : (H3 - 1)) * HH)
    const float* p0 = ROWP(r0)     + wid;   // chain w: element k = 8m+w
    const float* p1 = ROWP(r0 + 1) + wid;
    const float* p2 = ROWP(r0 + 2) + wid;
    const float* p3 = ROWP(r0 + 3) + wid;
    const float* p4 = ROWP(r0 + 4) + wid;
    const float* p5 = ROWP(r0 + 5) + wid;
    const float* p6 = ROWP(r0 + 6) + wid;
    const float* p7 = ROWP(r0 + 7) + wid;

    // m = 0..17 into explicit regs, slot m at byte offset 32*m. Pair-sets
    // (even-aligned): A rows (j0,j1) = v[100+2m], B (j2,j3) = v[138+2m],
    // C (j4,j5) = v[176+2m], D (j6,j7) = v[214+2m].
    asm volatile(
        LD8(100,101,138,139,176,177,214,215, 0)
        LD8(102,103,140,141,178,179,216,217, 32)
        LD8(104,105,142,143,180,181,218,219, 64)
        LD8(106,107,144,145,182,183,220,221, 96)
        LD8(108,109,146,147,184,185,222,223, 128)
        LD8(110,111,148,149,186,187,224,225, 160)
        LD8(112,113,150,151,188,189,226,227, 192)
        LD8(114,115,152,153,190,191,228,229, 224)
        LD8(116,117,154,155,192,193,230,231, 256)
        LD8(118,119,156,157,194,195,232,233, 288)
        LD8(120,121,158,159,196,197,234,235, 320)
        LD8(122,123,160,161,198,199,236,237, 352)
        LD8(124,125,162,163,200,201,238,239, 384)
        LD8(126,127,164,165,202,203,240,241, 416)
        LD8(128,129,166,167,204,205,242,243, 448)
        LD8(130,131,168,169,206,207,244,245, 480)
        LD8(132,133,170,171,208,209,246,247, 512)
        LD8(134,135,172,173,210,211,248,249, 544)
        "s_waitcnt vmcnt(0)\n\t"
        :
        : [p0] "v"(p0), [p1] "v"(p1), [p2] "v"(p2), [p3] "v"(p3),
          [p4] "v"(p4), [p5] "v"(p5), [p6] "v"(p6), [p7] "v"(p7)
        : WCLOB, "memory");
    // m = 18: k = 144+wid. Real for wid<6; for wid>=6 h[150..151]=0 forever
    // (hb slots never written), so load in-bounds junk (k=136+wid).
    {
        const int t18 = (wid < 6) ? 144 : 136;
        float w0 = p0[t18], w1 = p1[t18], w2 = p2[t18], w3 = p3[t18];
        float w4 = p4[t18], w5 = p5[t18], w6 = p6[t18], w7 = p7[t18];
        asm volatile(
            "v_mov_b32 v136, %0\n\tv_mov_b32 v137, %1\n\t"
            "v_mov_b32 v174, %2\n\tv_mov_b32 v175, %3\n\t"
            "v_mov_b32 v212, %4\n\tv_mov_b32 v213, %5\n\t"
            "v_mov_b32 v250, %6\n\tv_mov_b32 v251, %7\n\t"
            :: "v"(w0), "v"(w1), "v"(w2), "v"(w3),
               "v"(w4), "v"(w5), "v"(w6), "v"(w7)
            : "v136","v137","v174","v175","v212","v213","v250","v251");
    }

    // Phase-2 constants (threads 0..149) -- gate math verbatim from R12.
    float wih_r = 0.f, wih_z = 0.f, wih_n = 0.f;
    float bih_r = 0.f, bih_z = 0.f, bih_n = 0.f;
    float bhh_r = 0.f, bhh_z = 0.f, bhh_n = 0.f;
    if (tid < HH) {
        wih_r = W_ih[tid];          bih_r = b_ih[tid];          bhh_r = b_hh[tid];
        wih_z = W_ih[HH + tid];     bih_z = b_ih[HH + tid];     bhh_z = b_hh[HH + tid];
        wih_n = W_ih[2 * HH + tid]; bih_n = b_ih[2 * HH + tid]; bhh_n = b_hh[2 * HH + tid];
    }
    const float blin = b_lin[0];
    float hreg = 0.f;
    float* outb = out + (size_t)b * TT;
    // Store pointer: 4 float2 (8B lane stride = 2-way alias = free).
    float2* st = (float2*)PPf + wid * 272 + lane;
    // Wave-uniform LDS byte address of this wave's h chain (hb + wid*288).
    // Apertures are 4GiB-aligned, so the low 32 bits of a generic shared
    // address are the LDS offset.
    const unsigned hva = (unsigned)(size_t)(&hb[wid * 72]);
    // Phase-2 read indices: row r -> float idx (((r&7)>>1)*68 + (r>>3))*2
    // + (r&1); chain offset +544 floats each. bank = (8p+2d+c) mod 32 over
    // a wave's (p,d,c) space = exactly 2-way (free).
    int ir = 0, iz = 0, in_ = 0;
    if (tid < HH) {
        int r;
        r = tid;        ir  = (((r & 7) >> 1) * 68 + (r >> 3)) * 2 + (r & 1);
        r = HH + tid;   iz  = (((r & 7) >> 1) * 68 + (r >> 3)) * 2 + (r & 1);
        r = 2*HH + tid; in_ = (((r & 7) >> 1) * 68 + (r >> 3)) * 2 + (r & 1);
    }
    const int iy = (1 * 68 + 56) * 2;   // row 450: p=1, g=56, c=0 -> 248

    __syncthreads();

    // ---- recurrence -----------------------------------------------------
    // Iteration t dots h_{t-1}; row 450 gives y_{t-1}. Extra iteration
    // t==TT supplies y_{TT-1}; its h-update is guarded off.
    for (int t = 0; t <= TT; ++t) {
        // phase 1: chain w of rows 8l..8l+7. h broadcasts arrive via 10
        // uniform-address ds_read_b64 (pair j = h slots 2j, 2j+1),
        // pipelined under the MACs with counted lgkmcnt.
        fx2 a01, a23, a45, a67;        // first-touched by PKML in slot 0
        asm volatile(
            "ds_read_b64 v[80:81], %[va] offset:0\n\t"
            "ds_read_b64 v[82:83], %[va] offset:8\n\t"
            "ds_read_b64 v[84:85], %[va] offset:16\n\t"
            "ds_read_b64 v[86:87], %[va] offset:24\n\t"
            "ds_read_b64 v[88:89], %[va] offset:32\n\t"
            "ds_read_b64 v[90:91], %[va] offset:40\n\t"
            "ds_read_b64 v[92:93], %[va] offset:48\n\t"
            "ds_read_b64 v[94:95], %[va] offset:56\n\t"
            "ds_read_b64 v[96:97], %[va] offset:64\n\t"
            "ds_read_b64 v[98:99], %[va] offset:72\n\t"
            "s_waitcnt lgkmcnt(8)\n\t"   // pairs 0,1 landed (tail-robust)
            S0("v[80:81]", "v[100:101]","v[138:139]","v[176:177]","v[214:215]")
            SH("v[80:81]", "v[102:103]","v[140:141]","v[178:179]","v[216:217]")
            SL("v[82:83]", "v[104:105]","v[142:143]","v[180:181]","v[218:219]")
            SH("v[82:83]", "v[106:107]","v[144:145]","v[182:183]","v[220:221]")
            "s_waitcnt lgkmcnt(6)\n\t"   // pairs 2,3
            SL("v[84:85]", "v[108:109]","v[146:147]","v[184:185]","v[222:223]")
            SH("v[84:85]", "v[110:111]","v[148:149]","v[186:187]","v[224:225]")
            SL("v[86:87]", "v[112:113]","v[150:151]","v[188:189]","v[226:227]")
            SH("v[86:87]", "v[114:115]","v[152:153]","v[190:191]","v[228:229]")
            "s_waitcnt lgkmcnt(4)\n\t"   // pairs 4,5
            SL("v[88:89]", "v[116:117]","v[154:155]","v[192:193]","v[230:231]")
            SH("v[88:89]", "v[118:119]","v[156:157]","v[194:195]","v[232:233]")
            SL("v[90:91]", "v[120:121]","v[158:159]","v[196:197]","v[234:235]")
            SH("v[90:91]", "v[122:123]","v[160:161]","v[198:199]","v[236:237]")
            "s_waitcnt lgkmcnt(2)\n\t"   // pairs 6,7
            SL("v[92:93]", "v[124:125]","v[162:163]","v[200:201]","v[238:239]")
            SH("v[92:93]", "v[126:127]","v[164:165]","v[202:203]","v[240:241]")
            SL("v[94:95]", "v[128:129]","v[166:167]","v[204:205]","v[242:243]")
            SH("v[94:95]", "v[130:131]","v[168:169]","v[206:207]","v[244:245]")
            "s_waitcnt lgkmcnt(0)\n\t"   // pairs 8,9
            SL("v[96:97]", "v[132:133]","v[170:171]","v[208:209]","v[246:247]")
            SH("v[96:97]", "v[134:135]","v[172:173]","v[210:211]","v[248:249]")
            SL("v[98:99]", "v[136:137]","v[174:175]","v[212:213]","v[250:251]")
            : [a01] "=&v"(a01), [a23] "=&v"(a23),
              [a45] "=&v"(a45), [a67] "=&v"(a67)
            : [va] "v"(hva)
            : HCLOB, WCLOB);
        // Four conflict-free b64 stores (8B lane stride).
        float2 s01; s01.x = a01.x; s01.y = a01.y;
        float2 s23; s23.x = a23.x; s23.y = a23.y;
        float2 s45; s45.x = a45.x; s45.y = a45.y;
        float2 s67; s67.x = a67.x; s67.y = a67.y;
        st[0]   = s01;
        st[68]  = s23;
        st[136] = s45;
        st[204] = s67;
        __syncthreads();

        // phase 2: gates + hidden update (threads 0..149), skipped at t==TT.
        // pre_row = (((c0+c1)+(c2+c3)) + ((c4+c5)+(c6+c7))) + bhh.
        if (t < TT && tid < HH) {
            float x  = xrow[t];
            float pr = (((PPf[ir]         + PPf[ir + 544])
                       + (PPf[ir + 1088]  + PPf[ir + 1632]))
                      + ((PPf[ir + 2176]  + PPf[ir + 2720])
                       + (PPf[ir + 3264]  + PPf[ir + 3808]))) + bhh_r;
            float pz = (((PPf[iz]         + PPf[iz + 544])
                       + (PPf[iz + 1088]  + PPf[iz + 1632]))
                      + ((PPf[iz + 2176]  + PPf[iz + 2720])
                       + (PPf[iz + 3264]  + PPf[iz + 3808]))) + bhh_z;
            float pn = (((PPf[in_]        + PPf[in_ + 544])
                       + (PPf[in_ + 1088] + PPf[in_ + 1632]))
                      + ((PPf[in_ + 2176] + PPf[in_ + 2720])
                       + (PPf[in_ + 3264] + PPf[in_ + 3808]))) + bhh_n;
            float gr = fmaf(x, wih_r, bih_r) + pr;
            float gz = fmaf(x, wih_z, bih_z) + pz;
            float r  = 1.f / (1.f + __expf(-gr));
            float z  = 1.f / (1.f + __expf(-gz));
            float ta = fmaf(x, wih_n, bih_n) + r * pn;
            ta = fminf(fmaxf(ta, -15.f), 15.f);
            float e  = __expf(2.f * ta);
            float n  = (e - 1.f) / (e + 1.f);        // tanh
            float hnew = fmaf(z, hreg - n, n);       // (1-z)*n + z*h
            hnew = fmaxf(hnew, 0.f);                 // relu
            hreg = hnew;
            hb[(tid & 7) * 72 + (tid >> 3)] = hnew;  // 2-way write alias
        }
        // y_{t-1} from phase-1 row 450 (same 8-term tree), wave 7.
        if (t > 0 && tid == H3) {
            yout[t - 1] = (((PPf[iy]        + PPf[iy + 544])
                          + (PPf[iy + 1088] + PPf[iy + 1632]))
                         + ((PPf[iy + 2176] + PPf[iy + 2720])
                          + (PPf[iy + 3264] + PPf[iy + 3808]))) + blin;
        }
        __syncthreads();
    }

    // ---- epilogue: coalesced y dump (the loop's only global write) -------
    ((float4*)outb)[tid] = ((const float4*)yout)[tid];
}

extern "C" void kernel_launch(void* const* d_in, const int* in_sizes, int n_in,
                              void* d_out, int out_size, void* d_ws, size_t ws_size,
                              hipStream_t stream) {
    const float* input = (const float*)d_in[0];
    const float* W_ih  = (const float*)d_in[1];
    const float* W_hh  = (const float*)d_in[2];
    const float* b_ih  = (const float*)d_in[3];
    const float* b_hh  = (const float*)d_in[4];
    const float* W_lin = (const float*)d_in[5];
    const float* b_lin = (const float*)d_in[6];
    float* out = (float*)d_out;

    gru_seq_kernel<<<dim3(BB), dim3(512), 0, stream>>>(
        input, W_ih, W_hh, b_ih, b_hh, W_lin, b_lin, out);
}

// Round 12
// 1570.953 us; speedup vs baseline: 1.8768x; 1.0571x over previous
//
#include <hip/hip_runtime.h>
#include <math.h>

// B=256, T=2048, H=150. Sequential GRU, relu'd hidden, scalar linear head.
// 1 block / batch element (256 blocks = 256 CUs), 512 threads.
//
// R24 = R23 (verified 1660us: uniform-address ds_read_b64 h-broadcast +
// op_sel, counted lgkmcnt pipelining) with P2's THREE IEEE divides
// replaced by v_rcp_f32 (1-ulp HW reciprocal) + multiply:
//   r = rcp(1+e^-gr), z = rcp(1+e^-gz), n = (e-1)*rcp(e+1).
// Without fast-math each strict divide is ~10 insts / ~25-35 dependent
// cycles (div_scale/rcp/Newton/div_fmas/div_fixup); all three sit on the
// h(t)->h(t+1) serial chain inside the 3-wave P2 phase. NUMERICS-AFFECTING
// (~1ulp/gate): absmax may shift from 4.88e-4; threshold 1.71e-3 has 3.5x
// margin; contractive gates bound accumulation. Pre-commit: revert if
// absmax > 1.2e-3.
// Ledger: h-transport solved (R23, -7%); bank geometry solved (R17);
// P1 batching +65% (R21); P2 spread +9/+15% (R13/R16); LDS atomics 6.6x
// (R19); issue micros neutral (R15/R18).

#define BB 256
#define TT 2048
#define HH 150
#define H3 450

typedef float fx2 __attribute__((ext_vector_type(2)));

// Clobber list for explicit weight registers v100..v251.
#define WCLOB \
  "v100","v101","v102","v103","v104","v105","v106","v107","v108","v109", \
  "v110","v111","v112","v113","v114","v115","v116","v117","v118","v119", \
  "v120","v121","v122","v123","v124","v125","v126","v127","v128","v129", \
  "v130","v131","v132","v133","v134","v135","v136","v137","v138","v139", \
  "v140","v141","v142","v143","v144","v145","v146","v147","v148","v149", \
  "v150","v151","v152","v153","v154","v155","v156","v157","v158","v159", \
  "v160","v161","v162","v163","v164","v165","v166","v167","v168","v169", \
  "v170","v171","v172","v173","v174","v175","v176","v177","v178","v179", \
  "v180","v181","v182","v183","v184","v185","v186","v187","v188","v189", \
  "v190","v191","v192","v193","v194","v195","v196","v197","v198","v199", \
  "v200","v201","v202","v203","v204","v205","v206","v207","v208","v209", \
  "v210","v211","v212","v213","v214","v215","v216","v217","v218","v219", \
  "v220","v221","v222","v223","v224","v225","v226","v227","v228","v229", \
  "v230","v231","v232","v233","v234","v235","v236","v237","v238","v239", \
  "v240","v241","v242","v243","v244","v245","v246","v247","v248","v249", \
  "v250","v251"

// h-broadcast scratch pairs v[80:81]..v[98:99].
#define HCLOB \
  "v80","v81","v82","v83","v84","v85","v86","v87","v88","v89", \
  "v90","v91","v92","v93","v94","v95","v96","v97","v98","v99"

// Load one k-slot (slot m at byte offset 32*m) for all 8 rows.
#define LD8(a0,a1,b0,b1,c0,c1,d0,d1,OFF) \
  "global_load_dword v" #a0 ", %[p0], off offset:" #OFF "\n\t" \
  "global_load_dword v" #a1 ", %[p1], off offset:" #OFF "\n\t" \
  "global_load_dword v" #b0 ", %[p2], off offset:" #OFF "\n\t" \
  "global_load_dword v" #b1 ", %[p3], off offset:" #OFF "\n\t" \
  "global_load_dword v" #c0 ", %[p4], off offset:" #OFF "\n\t" \
  "global_load_dword v" #c1 ", %[p5], off offset:" #OFF "\n\t" \
  "global_load_dword v" #d0 ", %[p6], off offset:" #OFF "\n\t" \
  "global_load_dword v" #d1 ", %[p7], off offset:" #OFF "\n\t"

// pk_fma / pk_mul with broadcast from LOW or HIGH word of VGPR pair hp.
#define PKBL(hp, wp, acc) \
  "v_pk_fma_f32 " acc ", " hp ", " wp ", " acc " op_sel:[0,0,0] op_sel_hi:[0,1,1]\n\t"
#define PKBH(hp, wp, acc) \
  "v_pk_fma_f32 " acc ", " hp ", " wp ", " acc " op_sel:[1,0,0] op_sel_hi:[1,1,1]\n\t"
#define PKML(hp, wp, acc) \
  "v_pk_mul_f32 " acc ", " hp ", " wp " op_sel:[0,0] op_sel_hi:[0,1]\n\t"

// One k-slot = 4 chains. S0 = first touch (pk_mul), SL = low word,
// SH = high word of the h pair.
#define S0(P, A,B,C,D) \
  PKML(P, A, "%[a01]") PKML(P, B, "%[a23]") \
  PKML(P, C, "%[a45]") PKML(P, D, "%[a67]")
#define SL(P, A,B,C,D) \
  PKBL(P, A, "%[a01]") PKBL(P, B, "%[a23]") \
  PKBL(P, C, "%[a45]") PKBL(P, D, "%[a67]")
#define SH(P, A,B,C,D) \
  PKBH(P, A, "%[a01]") PKBH(P, B, "%[a23]") \
  PKBH(P, C, "%[a45]") PKBH(P, D, "%[a67]")

__global__ __launch_bounds__(512, 2) void gru_seq_kernel(
    const float* __restrict__ input,   // [B,T]
    const float* __restrict__ W_ih,    // [450,1]
    const float* __restrict__ W_hh,    // [450,150]
    const float* __restrict__ b_ih,    // [450]
    const float* __restrict__ b_hh,    // [450]
    const float* __restrict__ W_lin,   // [1,150]
    const float* __restrict__ b_lin,   // [1]
    float* __restrict__ out)           // [B,T]
{
    const int b    = blockIdx.x;
    const int tid  = threadIdx.x;
    const int lane = tid & 63;
    const int wid  = tid >> 6;               // 0..7 = chain (k mod 8)

    __shared__ float xrow[TT];         // 8 KB input row
    __shared__ float PPf[4352];        // 17.4 KB partials:
                                       // float2-idx = w*272 + p*68 + lane
    __shared__ __align__(16) float hb[640];  // h: hb[(u&7)*72 + (u>>3)]
    __shared__ float yout[TT];         // 8 KB y buffer

    // ---- prologue -------------------------------------------------------
    ((float4*)xrow)[tid] = ((const float4*)(input + (size_t)b * TT))[tid];
    hb[tid] = 0.f;                     // 0..511
    if (tid < 128) hb[512 + tid] = 0.f;

    // Rows 8*lane..8*lane+7. Row 450 = W_lin (y-row). Row >=451: clamp to
    // 449 (junk partials stored but never read).
    const int r0 = 8 * lane;
#define ROWP(r) ((r) == H3 ? W_lin : W_hh + ((r) < H3 ? (r) : (H3 - 1)) * HH)
    const float* p0 = ROWP(r0)     + wid;   // chain w: element k = 8m+w
    const float* p1 = ROWP(r0 + 1) + wid;
    const float* p2 = ROWP(r0 + 2) + wid;
    const float* p3 = ROWP(r0 + 3) + wid;
    const float* p4 = ROWP(r0 + 4) + wid;
    const float* p5 = ROWP(r0 + 5) + wid;
    const float* p6 = ROWP(r0 + 6) + wid;
    const float* p7 = ROWP(r0 + 7) + wid;

    // m = 0..17 into explicit regs, slot m at byte offset 32*m. Pair-sets
    // (even-aligned): A rows (j0,j1) = v[100+2m], B (j2,j3) = v[138+2m],
    // C (j4,j5) = v[176+2m], D (j6,j7) = v[214+2m].
    asm volatile(
        LD8(100,101,138,139,176,177,214,215, 0)
        LD8(102,103,140,141,178,179,216,217, 32)
        LD8(104,105,142,143,180,181,218,219, 64)
        LD8(106,107,144,145,182,183,220,221, 96)
        LD8(108,109,146,147,184,185,222,223, 128)
        LD8(110,111,148,149,186,187,224,225, 160)
        LD8(112,113,150,151,188,189,226,227, 192)
        LD8(114,115,152,153,190,191,228,229, 224)
        LD8(116,117,154,155,192,193,230,231, 256)
        LD8(118,119,156,157,194,195,232,233, 288)
        LD8(120,121,158,159,196,197,234,235, 320)
        LD8(122,123,160,161,198,199,236,237, 352)
        LD8(124,125,162,163,200,201,238,239, 384)
        LD8(126,127,164,165,202,203,240,241, 416)
        LD8(128,129,166,167,204,205,242,243, 448)
        LD8(130,131,168,169,206,207,244,245, 480)
        LD8(132,133,170,171,208,209,246,247, 512)
        LD8(134,135,172,173,210,211,248,249, 544)
        "s_waitcnt vmcnt(0)\n\t"
        :
        : [p0] "v"(p0), [p1] "v"(p1), [p2] "v"(p2), [p3] "v"(p3),
          [p4] "v"(p4), [p5] "v"(p5), [p6] "v"(p6), [p7] "v"(p7)
        : WCLOB, "memory");
    // m = 18: k = 144+wid. Real for wid<6; for wid>=6 h[150..151]=0 forever
    // (hb slots never written), so load in-bounds junk (k=136+wid).
    {
        const int t18 = (wid < 6) ? 144 : 136;
        float w0 = p0[t18], w1 = p1[t18], w2 = p2[t18], w3 = p3[t18];
        float w4 = p4[t18], w5 = p5[t18], w6 = p6[t18], w7 = p7[t18];
        asm volatile(
            "v_mov_b32 v136, %0\n\tv_mov_b32 v137, %1\n\t"
            "v_mov_b32 v174, %2\n\tv_mov_b32 v175, %3\n\t"
            "v_mov_b32 v212, %4\n\tv_mov_b32 v213, %5\n\t"
            "v_mov_b32 v250, %6\n\tv_mov_b32 v251, %7\n\t"
            :: "v"(w0), "v"(w1), "v"(w2), "v"(w3),
               "v"(w4), "v"(w5), "v"(w6), "v"(w7)
            : "v136","v137","v174","v175","v212","v213","v250","v251");
    }

    // Phase-2 constants (threads 0..149) -- gate math verbatim from R12.
    float wih_r = 0.f, wih_z = 0.f, wih_n = 0.f;
    float bih_r = 0.f, bih_z = 0.f, bih_n = 0.f;
    float bhh_r = 0.f, bhh_z = 0.f, bhh_n = 0.f;
    if (tid < HH) {
        wih_r = W_ih[tid];          bih_r = b_ih[tid];          bhh_r = b_hh[tid];
        wih_z = W_ih[HH + tid];     bih_z = b_ih[HH + tid];     bhh_z = b_hh[HH + tid];
        wih_n = W_ih[2 * HH + tid]; bih_n = b_ih[2 * HH + tid]; bhh_n = b_hh[2 * HH + tid];
    }
    const float blin = b_lin[0];
    float hreg = 0.f;
    float* outb = out + (size_t)b * TT;
    // Store pointer: 4 float2 (8B lane stride = 2-way alias = free).
    float2* st = (float2*)PPf + wid * 272 + lane;
    // Wave-uniform LDS byte address of this wave's h chain (hb + wid*288).
    const unsigned hva = (unsigned)(size_t)(&hb[wid * 72]);
    // Phase-2 read indices: row r -> float idx (((r&7)>>1)*68 + (r>>3))*2
    // + (r&1); chain offset +544 floats each. 2-way bank alias (free).
    int ir = 0, iz = 0, in_ = 0;
    if (tid < HH) {
        int r;
        r = tid;        ir  = (((r & 7) >> 1) * 68 + (r >> 3)) * 2 + (r & 1);
        r = HH + tid;   iz  = (((r & 7) >> 1) * 68 + (r >> 3)) * 2 + (r & 1);
        r = 2*HH + tid; in_ = (((r & 7) >> 1) * 68 + (r >> 3)) * 2 + (r & 1);
    }
    const int iy = (1 * 68 + 56) * 2;   // row 450: p=1, g=56, c=0 -> 248

    __syncthreads();

    // ---- recurrence -----------------------------------------------------
    // Iteration t dots h_{t-1}; row 450 gives y_{t-1}. Extra iteration
    // t==TT supplies y_{TT-1}; its h-update is guarded off.
    for (int t = 0; t <= TT; ++t) {
        // phase 1: chain w of rows 8l..8l+7. h broadcasts arrive via 10
        // uniform-address ds_read_b64, pipelined under MACs (counted
        // lgkmcnt, tail-robust).
        fx2 a01, a23, a45, a67;        // first-touched by PKML in slot 0
        asm volatile(
            "ds_read_b64 v[80:81], %[va] offset:0\n\t"
            "ds_read_b64 v[82:83], %[va] offset:8\n\t"
            "ds_read_b64 v[84:85], %[va] offset:16\n\t"
            "ds_read_b64 v[86:87], %[va] offset:24\n\t"
            "ds_read_b64 v[88:89], %[va] offset:32\n\t"
            "ds_read_b64 v[90:91], %[va] offset:40\n\t"
            "ds_read_b64 v[92:93], %[va] offset:48\n\t"
            "ds_read_b64 v[94:95], %[va] offset:56\n\t"
            "ds_read_b64 v[96:97], %[va] offset:64\n\t"
            "ds_read_b64 v[98:99], %[va] offset:72\n\t"
            "s_waitcnt lgkmcnt(8)\n\t"   // pairs 0,1 landed (tail-robust)
            S0("v[80:81]", "v[100:101]","v[138:139]","v[176:177]","v[214:215]")
            SH("v[80:81]", "v[102:103]","v[140:141]","v[178:179]","v[216:217]")
            SL("v[82:83]", "v[104:105]","v[142:143]","v[180:181]","v[218:219]")
            SH("v[82:83]", "v[106:107]","v[144:145]","v[182:183]","v[220:221]")
            "s_waitcnt lgkmcnt(6)\n\t"   // pairs 2,3
            SL("v[84:85]", "v[108:109]","v[146:147]","v[184:185]","v[222:223]")
            SH("v[84:85]", "v[110:111]","v[148:149]","v[186:187]","v[224:225]")
            SL("v[86:87]", "v[112:113]","v[150:151]","v[188:189]","v[226:227]")
            SH("v[86:87]", "v[114:115]","v[152:153]","v[190:191]","v[228:229]")
            "s_waitcnt lgkmcnt(4)\n\t"   // pairs 4,5
            SL("v[88:89]", "v[116:117]","v[154:155]","v[192:193]","v[230:231]")
            SH("v[88:89]", "v[118:119]","v[156:157]","v[194:195]","v[232:233]")
            SL("v[90:91]", "v[120:121]","v[158:159]","v[196:197]","v[234:235]")
            SH("v[90:91]", "v[122:123]","v[160:161]","v[198:199]","v[236:237]")
            "s_waitcnt lgkmcnt(2)\n\t"   // pairs 6,7
            SL("v[92:93]", "v[124:125]","v[162:163]","v[200:201]","v[238:239]")
            SH("v[92:93]", "v[126:127]","v[164:165]","v[202:203]","v[240:241]")
            SL("v[94:95]", "v[128:129]","v[166:167]","v[204:205]","v[242:243]")
            SH("v[94:95]", "v[130:131]","v[168:169]","v[206:207]","v[244:245]")
            "s_waitcnt lgkmcnt(0)\n\t"   // pairs 8,9
            SL("v[96:97]", "v[132:133]","v[170:171]","v[208:209]","v[246:247]")
            SH("v[96:97]", "v[134:135]","v[172:173]","v[210:211]","v[248:249]")
            SL("v[98:99]", "v[136:137]","v[174:175]","v[212:213]","v[250:251]")
            : [a01] "=&v"(a01), [a23] "=&v"(a23),
              [a45] "=&v"(a45), [a67] "=&v"(a67)
            : [va] "v"(hva)
            : HCLOB, WCLOB);
        // Four conflict-free b64 stores (8B lane stride).
        float2 s01; s01.x = a01.x; s01.y = a01.y;
        float2 s23; s23.x = a23.x; s23.y = a23.y;
        float2 s45; s45.x = a45.x; s45.y = a45.y;
        float2 s67; s67.x = a67.x; s67.y = a67.y;
        st[0]   = s01;
        st[68]  = s23;
        st[136] = s45;
        st[204] = s67;
        __syncthreads();

        // phase 2: gates + hidden update (threads 0..149), skipped at t==TT.
        // pre_row = (((c0+c1)+(c2+c3)) + ((c4+c5)+(c6+c7))) + bhh.
        // Divides replaced by v_rcp_f32 (1-ulp) + mul: r,z,n.
        if (t < TT && tid < HH) {
            float x  = xrow[t];
            float pr = (((PPf[ir]         + PPf[ir + 544])
                       + (PPf[ir + 1088]  + PPf[ir + 1632]))
                      + ((PPf[ir + 2176]  + PPf[ir + 2720])
                       + (PPf[ir + 3264]  + PPf[ir + 3808]))) + bhh_r;
            float pz = (((PPf[iz]         + PPf[iz + 544])
                       + (PPf[iz + 1088]  + PPf[iz + 1632]))
                      + ((PPf[iz + 2176]  + PPf[iz + 2720])
                       + (PPf[iz + 3264]  + PPf[iz + 3808]))) + bhh_z;
            float pn = (((PPf[in_]        + PPf[in_ + 544])
                       + (PPf[in_ + 1088] + PPf[in_ + 1632]))
                      + ((PPf[in_ + 2176] + PPf[in_ + 2720])
                       + (PPf[in_ + 3264] + PPf[in_ + 3808]))) + bhh_n;
            float gr = fmaf(x, wih_r, bih_r) + pr;
            float gz = fmaf(x, wih_z, bih_z) + pz;
            float r  = __builtin_amdgcn_rcpf(1.f + __expf(-gr));
            float z  = __builtin_amdgcn_rcpf(1.f + __expf(-gz));
            float ta = fmaf(x, wih_n, bih_n) + r * pn;
            ta = fminf(fmaxf(ta, -15.f), 15.f);
            float e  = __expf(2.f * ta);
            float n  = (e - 1.f) * __builtin_amdgcn_rcpf(e + 1.f);  // tanh
            float hnew = fmaf(z, hreg - n, n);       // (1-z)*n + z*h
            hnew = fmaxf(hnew, 0.f);                 // relu
            hreg = hnew;
            hb[(tid & 7) * 72 + (tid >> 3)] = hnew;  // 2-way write alias
        }
        // y_{t-1} from phase-1 row 450 (same 8-term tree), wave 7.
        if (t > 0 && tid == H3) {
            yout[t - 1] = (((PPf[iy]        + PPf[iy + 544])
                          + (PPf[iy + 1088] + PPf[iy + 1632]))
                         + ((PPf[iy + 2176] + PPf[iy + 2720])
                          + (PPf[iy + 3264] + PPf[iy + 3808]))) + blin;
        }
        __syncthreads();
    }

    // ---- epilogue: coalesced y dump (the loop's only global write) -------
    ((float4*)outb)[tid] = ((const float4*)yout)[tid];
}

extern "C" void kernel_launch(void* const* d_in, const int* in_sizes, int n_in,
                              void* d_out, int out_size, void* d_ws, size_t ws_size,
                              hipStream_t stream) {
    const float* input = (const float*)d_in[0];
    const float* W_ih  = (const float*)d_in[1];
    const float* W_hh  = (const float*)d_in[2];
    const float* b_ih  = (const float*)d_in[3];
    const float* b_hh  = (const float*)d_in[4];
    const float* W_lin = (const float*)d_in[5];
    const float* b_lin = (const float*)d_in[6];
    float* out = (float*)d_out;

    gru_seq_kernel<<<dim3(BB), dim3(512), 0, stream>>>(
        input, W_ih, W_hh, b_ih, b_hh, W_lin, b_lin, out);
}